// Round 9
// baseline (3213.364 us; speedup 1.0000x reference)
//
#include <hip/hip_runtime.h>

#define MWIN 2048
#define HH 8

typedef _Float16 half8 __attribute__((ext_vector_type(8)));
typedef _Float16 half4 __attribute__((ext_vector_type(4)));
typedef float f32x4 __attribute__((ext_vector_type(4)));

// XCD-chunked window swizzle: 3x3 pooling neighbors (w +-1, +-32) stay in the
// same XCD L2. In block-id space neighbor deps are bid+-8 and bid+-248..264;
// guaranteed co-residency (>=2 blocks/CU = 512 blocks) exceeds the max dep
// distance 264, and HW dispatches ascending IDs => soft-barrier can't deadlock.
__device__ __forceinline__ int win_swz(int bid) {
    return (bid & 7) * 256 + (bid >> 3);
}

// ---- weight prep: fragmentize Wqkv/Wproj fp32 -> MFMA-fragment fp16.
// Block 32 zeroes the per-window dataflow flags (ws is poisoned each iter).
__global__ __launch_bounds__(256) void k_prep_w(const float* __restrict__ Wqkv,
                                                const float* __restrict__ Wproj,
                                                _Float16* __restrict__ fq,
                                                _Float16* __restrict__ fp,
                                                int* __restrict__ flags) {
    if (blockIdx.x == 32) {
        int4 z = {0, 0, 0, 0};
        ((int4*)flags)[threadIdx.x * 2] = z;
        ((int4*)flags)[threadIdx.x * 2 + 1] = z;
        return;
    }
    int tid = blockIdx.x * 256 + threadIdx.x;
    const float* src;
    _Float16* dst;
    if (tid < 6144) { src = Wqkv; dst = fq; }
    else {
        tid -= 6144;
        if (tid >= 2048) return;
        src = Wproj; dst = fp;
    }
    int lane = tid & 63, r = tid >> 6;
    int ct = r & 3, ks = (r >> 2) & 3, cg = r >> 4;
    int m = lane & 15, q = lane >> 4;
    const float* s_ = src + (size_t)(cg * 64 + ct * 16 + m) * 128 + q * 8 + ks * 32;
    float4 f0 = *(const float4*)s_;
    float4 f1 = *(const float4*)(s_ + 4);
    half8 h;
    h[0] = (_Float16)f0.x; h[1] = (_Float16)f0.y; h[2] = (_Float16)f0.z; h[3] = (_Float16)f0.w;
    h[4] = (_Float16)f1.x; h[5] = (_Float16)f1.y; h[6] = (_Float16)f1.z; h[7] = (_Float16)f1.w;
    *(half8*)(dst + (size_t)tid * 8) = h;
}

// ---- fully fused per-window kernel: QKV GEMM + kv/s + [flag barrier] +
// 3x3 pool + attention + projection. One block (512 thr = 8 waves) per window.
// q NEVER leaves LDS (kills the 41MB q_h round-trip); phase-2 of window w only
// waits on its 9 neighbors' kv flags (release/acquire, agent scope), so late
// windows' phase-1 overlaps early windows' phase-2 instead of a full-GPU drain.
__global__ __launch_bounds__(512) void k_fused(const float* __restrict__ x,
                                               const half8* __restrict__ fq,
                                               const half8* __restrict__ fp,
                                               const float* __restrict__ bproj,
                                               const int* __restrict__ offsets,
                                               const int* __restrict__ counts,
                                               float* __restrict__ kv_t,
                                               float* __restrict__ sbuf,
                                               int* __restrict__ flags,
                                               float* __restrict__ out) {
    // ubh phases: A = xs[48][136] (13KB); B = kT+vT [8][16][72]x2 (36KB);
    // C = y_t[48][136] (13KB) + o_t[48][132] f32 (25.3KB) = 38.4KB total.
    __shared__ __attribute__((aligned(16))) _Float16 ubh[19200];
    __shared__ __attribute__((aligned(16))) _Float16 q_lds[48][136];
    _Float16 (*kT)[16][72] = (_Float16(*)[16][72])ubh;
    _Float16 (*vT)[16][72] = (_Float16(*)[16][72])(ubh + 9216);

    int w = win_swz(blockIdx.x);
    int off = offsets[w], cnt = counts[w];
    int tid = threadIdx.x;

    // ---- phase A: cooperative coalesced stage of x (48 rows x 32 float4) ----
    #pragma unroll
    for (int it = 0; it < 3; ++it) {
        int j = it * 512 + tid;
        int row = j >> 5, c4 = j & 31;
        int sr = row < cnt ? row : cnt - 1;
        float4 f = *(const float4*)(x + (size_t)(off + sr) * 128 + c4 * 4);
        half4 hv;
        hv[0] = (_Float16)f.x; hv[1] = (_Float16)f.y;
        hv[2] = (_Float16)f.z; hv[3] = (_Float16)f.w;
        *(half4*)&ubh[row * 136 + c4 * 4] = hv;
    }
    __syncthreads();

    int h = tid >> 6, lane = tid & 63;
    int m = lane & 15, q = lane >> 4;

    // A fragments from LDS into registers (xs dead afterwards)
    half8 a[3][4];
    #pragma unroll
    for (int rt = 0; rt < 3; ++rt)
        #pragma unroll
        for (int ks = 0; ks < 4; ++ks)
            a[rt][ks] = *(const half8*)&ubh[(rt * 16 + m) * 136 + q * 8 + ks * 32];
    __syncthreads();   // xs reads done; ubh becomes kT/vT

    // zero-fill kT/vT positions 48..63
    {
        int zh = tid >> 6, zd = (tid >> 2) & 15, zp = 48 + (tid & 3) * 4;
        *(half4*)&kT[zh][zd][zp] = (half4){};
        *(half4*)&vT[zh][zd][zp] = (half4){};
    }

    // ---- phase B: QKV GEMM. wave h owns col-tiles ctg = 3h..3h+2 ----
    #pragma unroll
    for (int j = 0; j < 3; ++j) {
        int ctg = h * 3 + j;
        int cg = ctg >> 2, ctl = ctg & 3;
        half8 bfr[4];
        #pragma unroll
        for (int ks = 0; ks < 4; ++ks)
            bfr[ks] = fq[((size_t)cg * 16 + ks * 4 + ctl) * 64 + lane];
        #pragma unroll
        for (int rt = 0; rt < 3; ++rt) {
            f32x4 acc = {};
            #pragma unroll
            for (int ks = 0; ks < 4; ++ks)
                acc = __builtin_amdgcn_mfma_f32_16x16x32_f16(a[rt][ks], bfr[ks], acc, 0, 0, 0);
            int p0 = rt * 16 + q * 4;
            if (ctg < 8) {              // q cols: relu, row-major, stays in LDS
                #pragma unroll
                for (int reg = 0; reg < 4; ++reg)
                    q_lds[p0 + reg][ctg * 16 + m] = (_Float16)fmaxf(acc[reg], 0.f);
            } else if (ctg < 16) {      // k cols: relu + zero p>=cnt, transposed
                int head = ctg - 8;
                half4 hv;
                #pragma unroll
                for (int reg = 0; reg < 4; ++reg)
                    hv[reg] = (_Float16)((p0 + reg < cnt) ? fmaxf(acc[reg], 0.f) : 0.f);
                *(half4*)&kT[head][m][p0] = hv;
            } else {                    // v cols: transposed
                int head = ctg - 16;
                half4 hv;
                #pragma unroll
                for (int reg = 0; reg < 4; ++reg) hv[reg] = (_Float16)acc[reg];
                *(half4*)&vT[head][m][p0] = hv;
            }
        }
    }
    __syncthreads();

    // ---- kv = K^T V, s = K^T 1 via MFMA; wave h = head h ----
    {
        half8 a1 = *(const half8*)&kT[h][m][q * 8];
        half8 a2 = *(const half8*)&kT[h][m][32 + q * 8];
        half8 b1 = *(const half8*)&vT[h][m][q * 8];
        half8 b2 = *(const half8*)&vT[h][m][32 + q * 8];
        half8 ones;
        #pragma unroll
        for (int i = 0; i < 8; ++i) ones[i] = (_Float16)1.0f;
        f32x4 kva = {};
        kva = __builtin_amdgcn_mfma_f32_16x16x32_f16(a1, b1, kva, 0, 0, 0);
        kva = __builtin_amdgcn_mfma_f32_16x16x32_f16(a2, b2, kva, 0, 0, 0);
        f32x4 sa4 = {};
        sa4 = __builtin_amdgcn_mfma_f32_16x16x32_f16(a1, ones, sa4, 0, 0, 0);
        sa4 = __builtin_amdgcn_mfma_f32_16x16x32_f16(a2, ones, sa4, 0, 0, 0);
        *(f32x4*)(kv_t + (((size_t)(w * HH + h)) << 8) + m * 16 + q * 4) = kva;
        if (m == 0)
            *(f32x4*)(sbuf + (((size_t)(w * HH + h)) << 4) + q * 4) = sa4;
    }

    // ---- release: publish this window's kv/s ----
    __threadfence();       // per-thread: drain own stores, L2 writeback (agent)
    __syncthreads();
    if (tid == 0)
        __hip_atomic_store(&flags[w], 1, __ATOMIC_RELEASE, __HIP_MEMORY_SCOPE_AGENT);

    // ---- acquire: wait for the 9 pooling neighbors ----
    int b = w >> 10, yy = (w >> 5) & 31, xx = w & 31;
    if (tid < 9) {
        int dy = tid / 3 - 1, dx = tid % 3 - 1;
        int ny = yy + dy, nx = xx + dx;
        if (ny >= 0 && ny < 32 && nx >= 0 && nx < 32) {
            int nw = (b << 10) | (ny << 5) | nx;
            while (__hip_atomic_load(&flags[nw], __ATOMIC_ACQUIRE,
                                     __HIP_MEMORY_SCOPE_AGENT) == 0)
                __builtin_amdgcn_s_sleep(2);
        }
    }
    __syncthreads();
    __threadfence();       // invalidate stale cache lines before reading kv_t

    // ---- phase C: 3x3 pool + attention (q from LDS) + projection ----
    _Float16 (*y_t)[136] = (_Float16(*)[136])ubh;
    float (*o_t)[132] = (float(*)[132])((char*)ubh + 13056);

    int col = lane & 15;
    int kq = lane >> 4;
    bool klive = kq < 2;
    int koff = (kq & 1) * 8;

    f32x4 k0 = {}, k1 = {}, s0 = {}, s1 = {};
    if (klive) {
        #pragma unroll
        for (int dy = -1; dy <= 1; ++dy)
            #pragma unroll
            for (int dx = -1; dx <= 1; ++dx) {
                int ny = yy + dy, nx = xx + dx;
                if (ny < 0 || ny >= 32 || nx < 0 || nx >= 32) continue;
                int nw = (b << 10) | (ny << 5) | nx;
                const float* kb = kv_t + (((size_t)(nw * HH + h)) << 8) + col * 16 + koff;
                k0 += *(const f32x4*)kb;
                k1 += *(const f32x4*)(kb + 4);
                const float* sb = sbuf + (((size_t)(nw * HH + h)) << 4) + koff;
                s0 += *(const f32x4*)sb;
                s1 += *(const f32x4*)(sb + 4);
            }
    }
    half8 a_kv, a_s;
    #pragma unroll
    for (int i = 0; i < 4; ++i) {
        a_kv[i] = (_Float16)k0[i]; a_kv[4 + i] = (_Float16)k1[i];
        a_s[i]  = (_Float16)s0[i]; a_s[4 + i]  = (_Float16)s1[i];
    }

    #pragma unroll
    for (int c = 0; c < 3; ++c) {
        int p = c * 16 + col;
        int pc = p < cnt ? p : cnt - 1;
        half8 b_q = *(const half8*)&q_lds[pc][h * 16 + koff];
        f32x4 acc = {};
        acc = __builtin_amdgcn_mfma_f32_16x16x32_f16(a_kv, b_q, acc, 0, 0, 0);
        f32x4 accs = {};
        accs = __builtin_amdgcn_mfma_f32_16x16x32_f16(a_s, b_q, accs, 0, 0, 0);
        float zinv = 1.f / (accs[0] + 1e-6f);
        half4 yo;
        #pragma unroll
        for (int i = 0; i < 4; ++i) yo[i] = (_Float16)(acc[i] * zinv);
        *(half4*)&y_t[p][h * 16 + kq * 4] = yo;
    }
    __syncthreads();

    // projection: wave h owns output col-tile h
    {
        int cg = h >> 2, ctl = h & 3;
        half8 bfr[4];
        #pragma unroll
        for (int ks = 0; ks < 4; ++ks)
            bfr[ks] = fp[((size_t)cg * 16 + ks * 4 + ctl) * 64 + lane];
        float bv = bproj[h * 16 + m];
        #pragma unroll
        for (int rt = 0; rt < 3; ++rt) {
            f32x4 acc = (f32x4){bv, bv, bv, bv};
            #pragma unroll
            for (int ks = 0; ks < 4; ++ks) {
                half8 af = *(const half8*)&y_t[rt * 16 + m][q * 8 + ks * 32];
                acc = __builtin_amdgcn_mfma_f32_16x16x32_f16(af, bfr[ks], acc, 0, 0, 0);
            }
            #pragma unroll
            for (int reg = 0; reg < 4; ++reg)
                o_t[rt * 16 + q * 4 + reg][h * 16 + m] = acc[reg];
        }
    }
    __syncthreads();

    #pragma unroll
    for (int it = 0; it < 3; ++it) {
        int j = it * 512 + tid;
        int r = j >> 5, c4 = j & 31;
        if (r < cnt)
            *(float4*)(out + ((size_t)(off + r) << 7) + c4 * 4) = *(const float4*)&o_t[r][c4 * 4];
    }
}

extern "C" void kernel_launch(void* const* d_in, const int* in_sizes, int n_in,
                              void* d_out, int out_size, void* d_ws, size_t ws_size,
                              hipStream_t stream) {
    const float* x     = (const float*)d_in[0];
    const float* Wqkv  = (const float*)d_in[1];
    const float* Wproj = (const float*)d_in[2];
    const float* bproj = (const float*)d_in[3];
    const int*   offsets = (const int*)d_in[4];
    const int*   counts  = (const int*)d_in[5];

    char* ws = (char*)d_ws;
    float* kv_t = (float*)ws;                                    ws += (size_t)MWIN * HH * 256 * 4;
    float* s    = (float*)ws;                                    ws += (size_t)MWIN * HH * 16 * 4;
    _Float16* fq = (_Float16*)ws;                                ws += (size_t)6144 * 8 * 2;
    _Float16* fp = (_Float16*)ws;                                ws += (size_t)2048 * 8 * 2;
    int* flags  = (int*)ws;                                      ws += (size_t)MWIN * 4;
    float* out  = (float*)d_out;

    k_prep_w<<<33, 256, 0, stream>>>(Wqkv, Wproj, fq, fp, flags);

    k_fused<<<MWIN, 512, 0, stream>>>(x, (const half8*)fq, (const half8*)fp, bproj,
                                      offsets, counts, kv_t, s, flags, out);
}

// Round 10
// 145.410 us; speedup vs baseline: 22.0986x; 22.0986x over previous
//
#include <hip/hip_runtime.h>

#define MWIN 2048
#define HH 8

typedef _Float16 half8 __attribute__((ext_vector_type(8)));
typedef _Float16 half4 __attribute__((ext_vector_type(4)));
typedef float f32x4 __attribute__((ext_vector_type(4)));

// XCD-chunked window swizzle: 3x3 pooling neighbors (w +-1, +-32) stay in the
// same XCD L2 for both producer and consumer kernels.
__device__ __forceinline__ int win_swz(int bid) {
    return (bid & 7) * 256 + (bid >> 3);
}

// ---- weight prep: fragmentize Wqkv/Wproj fp32 -> MFMA-fragment fp16.
__global__ __launch_bounds__(256) void k_prep_w(const float* __restrict__ Wqkv,
                                                const float* __restrict__ Wproj,
                                                _Float16* __restrict__ fq,
                                                _Float16* __restrict__ fp) {
    int tid = blockIdx.x * 256 + threadIdx.x;
    const float* src;
    _Float16* dst;
    if (tid < 6144) { src = Wqkv; dst = fq; }
    else {
        tid -= 6144;
        if (tid >= 2048) return;
        src = Wproj; dst = fp;
    }
    int lane = tid & 63, r = tid >> 6;
    int ct = r & 3, ks = (r >> 2) & 3, cg = r >> 4;
    int m = lane & 15, q = lane >> 4;
    const float* s_ = src + (size_t)(cg * 64 + ct * 16 + m) * 128 + q * 8 + ks * 32;
    float4 f0 = *(const float4*)s_;
    float4 f1 = *(const float4*)(s_ + 4);
    half8 h;
    h[0] = (_Float16)f0.x; h[1] = (_Float16)f0.y; h[2] = (_Float16)f0.z; h[3] = (_Float16)f0.w;
    h[4] = (_Float16)f1.x; h[5] = (_Float16)f1.y; h[6] = (_Float16)f1.z; h[7] = (_Float16)f1.w;
    *(half8*)(dst + (size_t)tid * 8) = h;
}

// ---- per-window fused QKV GEMM + kv/s reduction (r8 structure) ----
__global__ __launch_bounds__(512) void k_qkv_win(const float* __restrict__ x,
                                                 const half8* __restrict__ fq,
                                                 const int* __restrict__ offsets,
                                                 const int* __restrict__ counts,
                                                 _Float16* __restrict__ q_h,
                                                 float* __restrict__ kv_t,
                                                 float* __restrict__ s) {
    // ubuf: phase A = xs[48][136] staging (13KB); phase B = kT+vT [8][16][72]x2
    __shared__ __attribute__((aligned(16))) _Float16 ubuf[18432];
    __shared__ __attribute__((aligned(16))) _Float16 q_lds[48][136];
    _Float16 (*kT)[16][72] = (_Float16(*)[16][72])ubuf;
    _Float16 (*vT)[16][72] = (_Float16(*)[16][72])(ubuf + 9216);

    int w = win_swz(blockIdx.x);
    int off = offsets[w], cnt = counts[w];
    int tid = threadIdx.x;

    // phase A: cooperative coalesced stage of x (48 rows x 32 float4)
    #pragma unroll
    for (int it = 0; it < 3; ++it) {
        int j = it * 512 + tid;
        int row = j >> 5, c4 = j & 31;
        int sr = row < cnt ? row : cnt - 1;
        float4 f = *(const float4*)(x + (size_t)(off + sr) * 128 + c4 * 4);
        half4 hv;
        hv[0] = (_Float16)f.x; hv[1] = (_Float16)f.y;
        hv[2] = (_Float16)f.z; hv[3] = (_Float16)f.w;
        *(half4*)&ubuf[row * 136 + c4 * 4] = hv;
    }
    __syncthreads();

    int h = tid >> 6, lane = tid & 63;
    int m = lane & 15, q = lane >> 4;

    // A fragments from LDS into registers (xs dead afterwards)
    half8 a[3][4];
    #pragma unroll
    for (int rt = 0; rt < 3; ++rt)
        #pragma unroll
        for (int ks = 0; ks < 4; ++ks)
            a[rt][ks] = *(const half8*)&ubuf[(rt * 16 + m) * 136 + q * 8 + ks * 32];
    __syncthreads();   // xs reads done; ubuf becomes kT/vT

    // zero-fill kT/vT positions 48..63
    {
        int zh = tid >> 6, zd = (tid >> 2) & 15, zp = 48 + (tid & 3) * 4;
        *(half4*)&kT[zh][zd][zp] = (half4){};
        *(half4*)&vT[zh][zd][zp] = (half4){};
    }

    // phase B: GEMM. wave h owns col-tiles ctg = 3h..3h+2
    #pragma unroll
    for (int j = 0; j < 3; ++j) {
        int ctg = h * 3 + j;
        int cg = ctg >> 2, ctl = ctg & 3;
        half8 bfr[4];
        #pragma unroll
        for (int ks = 0; ks < 4; ++ks)
            bfr[ks] = fq[((size_t)cg * 16 + ks * 4 + ctl) * 64 + lane];
        #pragma unroll
        for (int rt = 0; rt < 3; ++rt) {
            f32x4 acc = {};
            #pragma unroll
            for (int ks = 0; ks < 4; ++ks)
                acc = __builtin_amdgcn_mfma_f32_16x16x32_f16(a[rt][ks], bfr[ks], acc, 0, 0, 0);
            int p0 = rt * 16 + q * 4;
            if (ctg < 8) {              // q cols: relu, row-major for q_h store
                #pragma unroll
                for (int reg = 0; reg < 4; ++reg)
                    q_lds[p0 + reg][ctg * 16 + m] = (_Float16)fmaxf(acc[reg], 0.f);
            } else if (ctg < 16) {      // k cols: relu + zero p>=cnt, transposed
                int head = ctg - 8;
                half4 hv;
                #pragma unroll
                for (int reg = 0; reg < 4; ++reg)
                    hv[reg] = (_Float16)((p0 + reg < cnt) ? fmaxf(acc[reg], 0.f) : 0.f);
                *(half4*)&kT[head][m][p0] = hv;
            } else {                    // v cols: transposed
                int head = ctg - 16;
                half4 hv;
                #pragma unroll
                for (int reg = 0; reg < 4; ++reg) hv[reg] = (_Float16)acc[reg];
                *(half4*)&vT[head][m][p0] = hv;
            }
        }
    }
    __syncthreads();

    // relu'd q rows -> global (coalesced half8)
    #pragma unroll
    for (int it = 0; it < 2; ++it) {
        int idx = it * 512 + tid;
        int row = idx >> 4, c8 = idx & 15;
        if (row < cnt)
            *(half8*)(q_h + (size_t)(off + row) * 128 + c8 * 8) = *(const half8*)&q_lds[row][c8 * 8];
    }

    // kv = K^T V, s = K^T 1 via MFMA; wave h = head h
    half8 a1 = *(const half8*)&kT[h][m][q * 8];
    half8 a2 = *(const half8*)&kT[h][m][32 + q * 8];
    half8 b1 = *(const half8*)&vT[h][m][q * 8];
    half8 b2 = *(const half8*)&vT[h][m][32 + q * 8];
    half8 ones;
    #pragma unroll
    for (int i = 0; i < 8; ++i) ones[i] = (_Float16)1.0f;
    f32x4 kva = {};
    kva = __builtin_amdgcn_mfma_f32_16x16x32_f16(a1, b1, kva, 0, 0, 0);
    kva = __builtin_amdgcn_mfma_f32_16x16x32_f16(a2, b2, kva, 0, 0, 0);
    f32x4 sa4 = {};
    sa4 = __builtin_amdgcn_mfma_f32_16x16x32_f16(a1, ones, sa4, 0, 0, 0);
    sa4 = __builtin_amdgcn_mfma_f32_16x16x32_f16(a2, ones, sa4, 0, 0, 0);
    *(f32x4*)(kv_t + (((size_t)(w * HH + h)) << 8) + m * 16 + q * 4) = kva;
    if (m == 0)
        *(f32x4*)(s + (((size_t)(w * HH + h)) << 4) + q * 4) = sa4;
}

// ---------------- fused attn + 3x3 pool + output projection ----------------
// ROUND-10: (1) q window staged into LDS coalesced (was: per-lane 16-row x
// 256B-stride gather, 16 lines/instruction, x3 per wave). (2) o_t shrunk to a
// [16][132] slice, stored per proj step: LDS 34.3KB -> 4 blocks/CU (was 3).
__global__ __launch_bounds__(512) void k_attn_proj(const _Float16* __restrict__ q_h,
                                                   const float* __restrict__ kv_t,
                                                   const float* __restrict__ s,
                                                   const half8* __restrict__ fp,
                                                   const float* __restrict__ bproj,
                                                   const int* __restrict__ offsets,
                                                   const int* __restrict__ counts,
                                                   float* __restrict__ out) {
    __shared__ _Float16 q_s[48][136];
    __shared__ _Float16 y_t[48][136];
    __shared__ float o_t[16][132];
    int w = win_swz(blockIdx.x);
    int h = threadIdx.x >> 6;
    int lane = threadIdx.x & 63;
    int col = lane & 15;
    int kq = lane >> 4;
    int off = offsets[w], cnt = counts[w];
    bool klive = kq < 2;
    int koff = (kq & 1) * 8;
    int tid = threadIdx.x;

    // coalesced stage of q rows (clamped at cnt-1 so attention needs no clamp)
    #pragma unroll
    for (int it = 0; it < 2; ++it) {
        int j = it * 512 + tid;
        int row = j >> 4, c8 = j & 15;
        if (row < 48) {
            int sr = row < cnt ? row : cnt - 1;
            *(half8*)&q_s[row][c8 * 8] =
                *(const half8*)(q_h + (size_t)(off + sr) * 128 + c8 * 8);
        }
    }

    // 3x3 pool into fp32 regs (overlaps the q staging; no barrier needed yet)
    int b = w >> 10, yy = (w >> 5) & 31, xx = w & 31;
    f32x4 k0 = {}, k1 = {}, s0 = {}, s1 = {};
    if (klive) {
        #pragma unroll
        for (int dy = -1; dy <= 1; ++dy)
            #pragma unroll
            for (int dx = -1; dx <= 1; ++dx) {
                int ny = yy + dy, nx = xx + dx;
                if (ny < 0 || ny >= 32 || nx < 0 || nx >= 32) continue;
                int nw = (b << 10) | (ny << 5) | nx;
                const float* kb = kv_t + (((size_t)(nw * HH + h)) << 8) + col * 16 + koff;
                k0 += *(const f32x4*)kb;
                k1 += *(const f32x4*)(kb + 4);
                const float* sb = s + (((size_t)(nw * HH + h)) << 4) + koff;
                s0 += *(const f32x4*)sb;
                s1 += *(const f32x4*)(sb + 4);
            }
    }
    half8 a_kv, a_s;
    #pragma unroll
    for (int i = 0; i < 4; ++i) {
        a_kv[i] = (_Float16)k0[i]; a_kv[4 + i] = (_Float16)k1[i];
        a_s[i]  = (_Float16)s0[i]; a_s[4 + i]  = (_Float16)s1[i];
    }
    __syncthreads();   // q_s ready

    #pragma unroll
    for (int c = 0; c < 3; ++c) {
        int p = c * 16 + col;
        half8 b_q = *(const half8*)&q_s[p][h * 16 + koff];
        f32x4 acc = {};
        acc = __builtin_amdgcn_mfma_f32_16x16x32_f16(a_kv, b_q, acc, 0, 0, 0);
        f32x4 accs = {};
        accs = __builtin_amdgcn_mfma_f32_16x16x32_f16(a_s, b_q, accs, 0, 0, 0);
        float zinv = 1.f / (accs[0] + 1e-6f);
        half4 yo;
        #pragma unroll
        for (int i = 0; i < 4; ++i) yo[i] = (_Float16)(acc[i] * zinv);
        *(half4*)&y_t[p][h * 16 + kq * 4] = yo;
    }
    __syncthreads();

    // projection: wave h owns output col-tile h; one 16-row band per step
    int m = col, q = kq;
    int cg = h >> 2, ctl = h & 3;
    half8 bfr[4];
    #pragma unroll
    for (int ks = 0; ks < 4; ++ks)
        bfr[ks] = fp[((size_t)cg * 16 + ks * 4 + ctl) * 64 + lane];
    float bv = bproj[h * 16 + m];
    #pragma unroll
    for (int rt = 0; rt < 3; ++rt) {
        f32x4 acc = (f32x4){bv, bv, bv, bv};
        #pragma unroll
        for (int ks = 0; ks < 4; ++ks) {
            half8 af = *(const half8*)&y_t[rt * 16 + m][q * 8 + ks * 32];
            acc = __builtin_amdgcn_mfma_f32_16x16x32_f16(af, bfr[ks], acc, 0, 0, 0);
        }
        #pragma unroll
        for (int reg = 0; reg < 4; ++reg)
            o_t[q * 4 + reg][h * 16 + m] = acc[reg];
        __syncthreads();
        int r = tid >> 5, c4 = tid & 31;       // 16 rows x 32 float4 = 512 thr
        int grow = rt * 16 + r;
        if (grow < cnt)
            *(float4*)(out + ((size_t)(off + grow) << 7) + c4 * 4) = *(const float4*)&o_t[r][c4 * 4];
        __syncthreads();
    }
}

extern "C" void kernel_launch(void* const* d_in, const int* in_sizes, int n_in,
                              void* d_out, int out_size, void* d_ws, size_t ws_size,
                              hipStream_t stream) {
    const float* x     = (const float*)d_in[0];
    const float* Wqkv  = (const float*)d_in[1];
    const float* Wproj = (const float*)d_in[2];
    const float* bproj = (const float*)d_in[3];
    const int*   offsets = (const int*)d_in[4];
    const int*   counts  = (const int*)d_in[5];

    int N = in_sizes[0] / 128;

    char* ws = (char*)d_ws;
    float* kv_t = (float*)ws;                                    ws += (size_t)MWIN * HH * 256 * 4;
    float* s    = (float*)ws;                                    ws += (size_t)MWIN * HH * 16 * 4;
    _Float16* q_h    = (_Float16*)ws;                            ws += (size_t)N * 128 * 2;
    _Float16* fq     = (_Float16*)ws;                            ws += (size_t)6144 * 8 * 2;
    _Float16* fp     = (_Float16*)ws;                            ws += (size_t)2048 * 8 * 2;
    float* out  = (float*)d_out;

    k_prep_w<<<32, 256, 0, stream>>>(Wqkv, Wproj, fq, fp);

    k_qkv_win<<<MWIN, 512, 0, stream>>>(x, (const half8*)fq, offsets, counts,
                                        q_h, kv_t, s);

    k_attn_proj<<<MWIN, 512, 0, stream>>>(q_h, kv_t, s, (const half8*)fp, bproj,
                                          offsets, counts, out);
}